// Round 6
// baseline (303.503 us; speedup 1.0000x reference)
//
#include <hip/hip_runtime.h>
#include <math.h>
#include <string.h>

#define HH 2048
#define WW 2048
#define TSC 128                 // tile cols
#define TSR 32                  // tile rows
#define NBX (WW / TSC)          // 16
#define NBY (HH / TSR)          // 64
#define NTILES (NBX * NBY)      // 1024
#define NINT ((NBX - 2) * (NBY - 2))   // 868 interior tiles

struct Wts { float w[17][5]; float knorm; };

// angle index a: 0 -> -10deg, 1 -> 0deg, 2 -> +10deg
__host__ __device__ constexpr int js_fn(int a, int i) {
  return (a == 1) ? 2
       : (a == 2) ? ((i < 3) ? 0 : (i < 9) ? 1 : (i < 14) ? 2 : 3)
                  : ((i < 3) ? 3 : (i < 8) ? 2 : (i < 14) ? 1 : 0);
}
__host__ __device__ constexpr int nt_fn(int a, int i) {
  return (a == 1) ? 1 : (i == 8) ? 3 : 2;
}

__device__ __forceinline__ float fastrcp(float x) {
#if __has_builtin(__builtin_amdgcn_rcpf)
  return __builtin_amdgcn_rcpf(x);
#else
  return 1.0f / x;
#endif
}

// Difference-space pass, weights pre-divided by knorm = sum(k):
//  MODE 0: P0=X, P1=Y. LDS = Y-X.  Out = cen - acc            (= D1)
//  MODE 1: P0=D.       LDS = D.    Out = cen - acc            (= D2)
//  MODE 2: P0=D, P1=Y. LDS = D.    Out = Ycen - cen + acc     (= X3)
// Interior tiles: no bounds checks, no N read (N == knorm).
// Boundary tiles: checked staging, acc*knorm/N(pixel).
template <int ANGLE, int DENSE, int MODE>
__global__ __launch_bounds__(256, 5)
void conv_iter(const float* __restrict__ P0, const float* __restrict__ P1,
               const float* __restrict__ Nrm, float* __restrict__ Out, Wts wts)
{
  constexpr bool WIN8 = (DENSE || ANGLE != 1);  // angle 0 = single-column kernel
  constexpr int  LSTR = WIN8 ? 148 : 132;       // LDS row stride (floats, skewed)
  constexpr int  LCW  = WIN8 ? 36  : 32;        // staged float4 chunks per row
  constexpr int  XOFF = WIN8 ? 8   : 0;         // left halo cols staged
  constexpr int  CH   = 48 * LCW;               // total chunks: 1728 / 1536
  __shared__ float lds[48 * 148];               // 28416 B -> 5 blocks/CU

  // chunked XCD swizzle (gridDim.x = 1024*B, divisible by 8): each XCD gets a
  // contiguous band; interior decode is by-fastest so vertical-halo L2 hits.
  const int bid = blockIdx.x;
  const int wg  = (bid & 7) * (gridDim.x >> 3) + (bid >> 3);
  const int bz  = wg >> 10;                     // NTILES == 1024
  const int t0  = wg & 1023;
  int bx, by; bool interior;
  if (t0 < NINT) {
    interior = true;
    bx = 1 + t0 / (NBY - 2);
    by = 1 + t0 % (NBY - 2);
  } else {
    interior = false;
    const int u = t0 - NINT;
    if (u < NBX)          { bx = u;        by = 0; }
    else if (u < 2 * NBX) { bx = u - NBX;  by = NBY - 1; }
    else { const int v = u - 2 * NBX; by = 1 + (v >> 1); bx = (v & 1) ? NBX - 1 : 0; }
  }

  const int tid = threadIdx.x;
  const int x0  = bx * TSC;
  const int y0  = by * TSR;
  const size_t img = (size_t)bz * ((size_t)HH * WW);
  const float* A  = P0 + img;
  const float* Bp = (MODE == 1) ? nullptr : P1 + img;

  // ---- stage 48 x (128|144) window of (Y-X) or D into LDS ----
  if (interior) {
#pragma unroll
    for (int s = 0; s < (CH + 255) / 256; ++s) {
      const int idx = s * 256 + tid;
      if ((CH % 256 == 0) || idx < CH) {
        const int r  = idx / LCW;
        const int c4 = idx - r * LCW;
        const int gy = y0 - 8 + r;
        const int gx = x0 - XOFF + c4 * 4;
        const float* ap = A + (size_t)gy * WW + gx;
        float4 v;
        if (MODE == 0) {
          const float4 xa = *(const float4*)ap;
          const float4 yb = *(const float4*)(Bp + (size_t)gy * WW + gx);
          v = make_float4(yb.x - xa.x, yb.y - xa.y, yb.z - xa.z, yb.w - xa.w);
        } else {
          v = *(const float4*)ap;
        }
        *(float4*)(&lds[r * LSTR + c4 * 4]) = v;
      }
    }
  } else {
#pragma unroll
    for (int s = 0; s < (CH + 255) / 256; ++s) {
      const int idx = s * 256 + tid;
      if ((CH % 256 == 0) || idx < CH) {
        const int r  = idx / LCW;
        const int c4 = idx - r * LCW;
        const int gy = y0 - 8 + r;
        const int gx = x0 - XOFF + c4 * 4;
        float4 v = make_float4(0.f, 0.f, 0.f, 0.f);
        if (gy >= 0 && gy < HH) {
          const float* ar = A + (size_t)gy * WW;
          const float* br = (MODE == 0) ? (Bp + (size_t)gy * WW) : nullptr;
          if (gx >= 0 && gx + 4 <= WW) {
            if (MODE == 0) {
              const float4 xa = *(const float4*)(ar + gx);
              const float4 yb = *(const float4*)(br + gx);
              v = make_float4(yb.x - xa.x, yb.y - xa.y, yb.z - xa.z, yb.w - xa.w);
            } else {
              v = *(const float4*)(ar + gx);
            }
          } else {
            float tv[4] = {0.f, 0.f, 0.f, 0.f};
#pragma unroll
            for (int e = 0; e < 4; ++e) {
              const int gxe = gx + e;
              if (gxe >= 0 && gxe < WW)
                tv[e] = (MODE == 0) ? (br[gxe] - ar[gxe]) : ar[gxe];
            }
            v = make_float4(tv[0], tv[1], tv[2], tv[3]);
          }
        }
        *(float4*)(&lds[r * LSTR + c4 * 4]) = v;
      }
    }
  }
  __syncthreads();

  // ---- convolution from LDS: thread = 4 cols x 4 rows, diagonal reuse ----
  const int tc = tid & 31;                       // col-group 0..31
  const int tg = tid >> 5;                       // row-group 0..7 (4 rows each)
  const int lc = tc * 4;

  float acc[4][4];
#pragma unroll
  for (int t = 0; t < 4; ++t)
#pragma unroll
    for (int c = 0; c < 4; ++c) acc[t][c] = 0.0f;

#pragma unroll
  for (int rr = 0; rr < 20; ++rr) {
    const int lrow = tg * 4 + rr;
    const float* lp = &lds[lrow * LSTR];
    float win[WIN8 ? 8 : 4];
    if (WIN8) {
      const float2 w0 = *(const float2*)(lp + 6 + lc);
      const float4 w1 = *(const float4*)(lp + 8 + lc);
      const float2 w2 = *(const float2*)(lp + 12 + lc);
      win[0] = w0.x;  win[1] = w0.y;
      win[2] = w1.x;  win[3] = w1.y;  win[4] = w1.z;  win[5] = w1.w;
      win[6] = w2.x;  win[7] = w2.y;
    } else {
      const float4 w1 = *(const float4*)(lp + lc);
      win[0] = w1.x;  win[1] = w1.y;  win[2] = w1.z;  win[3] = w1.w;
    }
#pragma unroll
    for (int t = 0; t < 4; ++t) {
      const int i = rr - t;                      // compile-time after unroll
      if (i >= 0 && i <= 16) {
        const int js = DENSE ? 0 : js_fn(ANGLE, i);
        const int nt = DENSE ? 5 : nt_fn(ANGLE, i);
#pragma unroll
        for (int jj = 0; jj < nt; ++jj) {
          const float wv = wts.w[i][js + jj];    // kernarg -> SGPR
#pragma unroll
          for (int c = 0; c < 4; ++c)
            acc[t][c] = fmaf(wv, win[(WIN8 ? 0 : -2) + c + js + jj], acc[t][c]);
        }
      }
    }
  }

  // ---- epilogue: cen from LDS; boundary renormalizes by knorm/N ----
  float* Ob = Out + img;
  const int gx = x0 + lc;
  const float kn = wts.knorm;
#pragma unroll
  for (int t = 0; t < 4; ++t) {
    const int yo = y0 + tg * 4 + t;
    const float4 cv = *(const float4*)(&lds[(tg * 4 + t + 8) * LSTR + (WIN8 ? 8 : 0) + lc]);
    float a0 = acc[t][0], a1 = acc[t][1], a2 = acc[t][2], a3 = acc[t][3];
    if (!interior) {
      const float4 nv = *(const float4*)(Nrm + (size_t)yo * WW + gx);
      a0 = a0 * kn * fastrcp(nv.x);
      a1 = a1 * kn * fastrcp(nv.y);
      a2 = a2 * kn * fastrcp(nv.z);
      a3 = a3 * kn * fastrcp(nv.w);
    }
    float4 o;
    if (MODE == 2) {
      const float4 yv = *(const float4*)(Bp + (size_t)yo * WW + gx);
      o.x = yv.x - cv.x + a0;
      o.y = yv.y - cv.y + a1;
      o.z = yv.z - cv.z + a2;
      o.w = yv.w - cv.w + a3;
    } else {
      o.x = cv.x - a0;
      o.y = cv.y - a1;
      o.z = cv.z - a2;
      o.w = cv.w - a3;
    }
    *(float4*)(Ob + (size_t)yo * WW + gx) = o;
  }
}

// ---------------- host-side replication of _build_kernels ----------------

static void rotate33(const double* src, double* dst, double ang_deg) {
  const int n = 33;
  const double t = ang_deg * 3.14159265358979323846 / 180.0;
  const double cs = cos(t), sn = sin(t);
  for (int y = 0; y < n; ++y) {
    for (int x = 0; x < n; ++x) {
      const double y0 = y - 16.0, x0 = x - 16.0;
      const double sy = cs * y0 + sn * x0 + 16.0;
      const double sx = -sn * y0 + cs * x0 + 16.0;
      const double fy = floor(sy), fx = floor(sx);
      const int y0i = (int)fy, x0i = (int)fx;
      const double wy = sy - fy, wx = sx - fx;
      double o = 0.0;
      for (int dy = 0; dy < 2; ++dy)
        for (int dx = 0; dx < 2; ++dx) {
          const int yy = y0i + dy, xx = x0i + dx;
          if (yy < 0 || yy >= n || xx < 0 || xx >= n) continue;
          const double wgt = (dy ? wy : 1.0 - wy) * (dx ? wx : 1.0 - wx);
          o += wgt * src[yy * n + xx];
        }
      dst[y * n + x] = o;
    }
  }
}

static void build_K(float K[3][17][5]) {
  const double angs[3] = {-10.0, 0.0, 10.0};
  double base[33 * 33], rot[33 * 33];
  for (int i = 0; i < 33 * 33; ++i) base[i] = 0.0;
  for (int y = 0; y < 33; ++y) base[y * 33 + 16] = 1.0;  // ry==0 path
  for (int a = 0; a < 3; ++a) {
    if (a == 1) memcpy(rot, base, sizeof(rot));          // angle % 360 == 0
    else        rotate33(base, rot, angs[a]);
    double k17[17][17];
    for (int y = 0; y < 17; ++y)
      for (int x = 0; x < 17; ++x) k17[y][x] = rot[(y + 8) * 33 + (x + 8)];
    int r = 0, c = 0;
    for (int y = 0; y < 17; ++y) { bool nz = false; for (int x = 0; x < 17; ++x) if (k17[y][x] != 0.0) nz = true; r += nz; }
    for (int x = 0; x < 17; ++x) { bool nz = false; for (int y = 0; y < 17; ++y) if (k17[y][x] != 0.0) nz = true; c += nz; }
    r = r / 2 * 2; c = c / 2 * 2;
    const int kh = r + 1, kw = c + 1;
    for (int y = 0; y < 17; ++y)
      for (int x = 0; x < 5; ++x) K[a][y][x] = 0.0f;
    if (kh <= 17 && kw <= 5) {
      const int oh = (17 - kh) / 2, ow = (5 - kw) / 2;
      for (int y = 0; y < kh; ++y)
        for (int x = 0; x < kw; ++x)
          K[a][oh + y][ow + x] = (float)k17[8 - r / 2 + y][8 - c / 2 + x];
    }
  }
}

// 0 = structured (constexpr jstart/ntaps hold), 1 = dense 5-tap fallback
static int pick_mode(int a, const float K[17][5]) {
  for (int i = 0; i < 17; ++i) {
    const int js = js_fn(a, i), nt = nt_fn(a, i);
    for (int j = 0; j < 5; ++j)
      if ((j < js || j >= js + nt) && K[i][j] != 0.0f) return 1;
  }
  return 0;
}

template <int A, int MODE>
static void launch_iter(int dense, const float* P0, const float* P1, const float* Nrm,
                        float* Out, const Wts& w, int B, hipStream_t s) {
  dim3 grid(NTILES * B), blk(256);
  if (dense == 0) conv_iter<A, 0, MODE><<<grid, blk, 0, s>>>(P0, P1, Nrm, Out, w);
  else            conv_iter<A, 1, MODE><<<grid, blk, 0, s>>>(P0, P1, Nrm, Out, w);
}

extern "C" void kernel_launch(void* const* d_in, const int* in_sizes, int n_in,
                              void* d_out, int out_size, void* d_ws, size_t ws_size,
                              hipStream_t stream) {
  const float* X  = (const float*)d_in[0];
  const float* Y  = (const float*)d_in[1];
  const float* Nn = (const float*)d_in[3];
  float* out = (float*)d_out;
  float* tmp = (float*)d_ws;   // needs B*H*W*4 = 33.6 MB of scratch
  const size_t HW = (size_t)HH * WW;
  const int B = in_sizes[0] / (int)HW;   // 2

  float K[3][17][5];
  build_K(K);
  Wts w[3];
  for (int a = 0; a < 3; ++a) {
    double ks = 0.0;
    for (int i = 0; i < 17; ++i)
      for (int j = 0; j < 5; ++j) ks += K[a][i][j];
    const float kn = (float)ks;
    for (int i = 0; i < 17; ++i)
      for (int j = 0; j < 5; ++j) w[a].w[i][j] = K[a][i][j] / kn;
    w[a].knorm = kn;
  }
  const int m0 = pick_mode(0, K[0]);
  const int m1 = pick_mode(1, K[1]);
  const int m2 = pick_mode(2, K[2]);

  // D1 -> d_out, D2 -> d_ws, X3 -> d_out (never read+write same buffer in a pass)
  launch_iter<0, 0>(m0, X,   Y,       Nn,          out, w[0], B, stream);  // D1
  launch_iter<1, 1>(m1, out, nullptr, Nn + HW,     tmp, w[1], B, stream);  // D2
  launch_iter<2, 2>(m2, tmp, Y,       Nn + 2 * HW, out, w[2], B, stream);  // X3
}

// Round 7
// 101.985 us; speedup vs baseline: 2.9759x; 2.9759x over previous
//
#include <hip/hip_runtime.h>
#include <math.h>
#include <string.h>

#define HH 2048
#define WW 2048
#define TSC 128                 // tile cols
#define TSR 32                  // tile rows
#define NBX (WW / TSC)          // 16
#define NBY (HH / TSR)          // 64
#define NTILES (NBX * NBY)      // 1024
#define NINT ((NBX - 2) * (NBY - 2))   // 868 interior tiles

struct Wts { float w[17][5]; float knorm; };

// angle index a: 0 -> -10deg, 1 -> 0deg, 2 -> +10deg
__host__ __device__ constexpr int js_fn(int a, int i) {
  return (a == 1) ? 2
       : (a == 2) ? ((i < 3) ? 0 : (i < 9) ? 1 : (i < 14) ? 2 : 3)
                  : ((i < 3) ? 3 : (i < 8) ? 2 : (i < 14) ? 1 : 0);
}
__host__ __device__ constexpr int nt_fn(int a, int i) {
  return (a == 1) ? 1 : (i == 8) ? 3 : 2;
}

__device__ __forceinline__ float fastrcp(float x) {
#if __has_builtin(__builtin_amdgcn_rcpf)
  return __builtin_amdgcn_rcpf(x);
#else
  return 1.0f / x;
#endif
}

// Difference-space pass, weights pre-divided by knorm = sum(k):
//  MODE 0: P0=X, P1=Y. LDS = Y-X.  Out = cen - acc            (= D1)
//  MODE 1: P0=D.       LDS = D.    Out = cen - acc            (= D2)
//  MODE 2: P0=D, P1=Y. LDS = D.    Out = Ycen - cen + acc     (= X3)
// Interior tiles: no bounds checks, no N read (N == knorm there).
// Boundary tiles: checked staging, acc*knorm/N(pixel).
template <int ANGLE, int DENSE, int MODE>
__global__ __launch_bounds__(256, 3)   // r5-proven: no VGPR squeeze -> no spill
void conv_iter(const float* __restrict__ P0, const float* __restrict__ P1,
               const float* __restrict__ Nrm, float* __restrict__ Out, Wts wts)
{
  constexpr bool WIN8 = (DENSE || ANGLE != 1);  // angle 0 = single-column kernel
  constexpr int  LSTR = WIN8 ? 148 : 132;       // LDS row stride (floats, skewed)
  constexpr int  LCW  = WIN8 ? 36  : 32;        // staged float4 chunks per row
  constexpr int  XOFF = WIN8 ? 8   : 0;         // left halo cols staged
  constexpr int  CH   = 48 * LCW;               // total chunks: 1728 / 1536
  __shared__ float lds[48 * 148];               // 28416 B

  // chunked XCD swizzle (gridDim.x = 1024*B, divisible by 8): each XCD gets a
  // contiguous band; interior decode is by-fastest so vertical-halo L2 hits.
  const int bid = blockIdx.x;
  const int wg  = (bid & 7) * (gridDim.x >> 3) + (bid >> 3);
  const int bz  = wg >> 10;                     // NTILES == 1024
  const int t0  = wg & 1023;
  int bx, by; bool interior;
  if (t0 < NINT) {
    interior = true;
    bx = 1 + t0 / (NBY - 2);
    by = 1 + t0 % (NBY - 2);
  } else {
    interior = false;
    const int u = t0 - NINT;
    if (u < NBX)          { bx = u;        by = 0; }
    else if (u < 2 * NBX) { bx = u - NBX;  by = NBY - 1; }
    else { const int v = u - 2 * NBX; by = 1 + (v >> 1); bx = (v & 1) ? NBX - 1 : 0; }
  }

  const int tid = threadIdx.x;
  const int x0  = bx * TSC;
  const int y0  = by * TSR;
  const size_t img = (size_t)bz * ((size_t)HH * WW);
  const float* A  = P0 + img;
  const float* Bp = (MODE == 1) ? nullptr : P1 + img;

  // ---- stage 48 x (144|128) window of (Y-X) or D into LDS ----
  if (interior) {
#pragma unroll
    for (int s = 0; s < (CH + 255) / 256; ++s) {
      const int idx = s * 256 + tid;
      if ((CH % 256 == 0) || idx < CH) {
        const int r  = idx / LCW;
        const int c4 = idx - r * LCW;
        const int gy = y0 - 8 + r;
        const int gx = x0 - XOFF + c4 * 4;
        const float* ap = A + (size_t)gy * WW + gx;
        float4 v;
        if (MODE == 0) {
          const float4 xa = *(const float4*)ap;
          const float4 yb = *(const float4*)(Bp + (size_t)gy * WW + gx);
          v = make_float4(yb.x - xa.x, yb.y - xa.y, yb.z - xa.z, yb.w - xa.w);
        } else {
          v = *(const float4*)ap;
        }
        *(float4*)(&lds[r * LSTR + c4 * 4]) = v;
      }
    }
  } else {
#pragma unroll
    for (int s = 0; s < (CH + 255) / 256; ++s) {
      const int idx = s * 256 + tid;
      if ((CH % 256 == 0) || idx < CH) {
        const int r  = idx / LCW;
        const int c4 = idx - r * LCW;
        const int gy = y0 - 8 + r;
        const int gx = x0 - XOFF + c4 * 4;
        float4 v = make_float4(0.f, 0.f, 0.f, 0.f);
        if (gy >= 0 && gy < HH) {
          const float* ar = A + (size_t)gy * WW;
          const float* br = (MODE == 0) ? (Bp + (size_t)gy * WW) : nullptr;
          if (gx >= 0 && gx + 4 <= WW) {
            if (MODE == 0) {
              const float4 xa = *(const float4*)(ar + gx);
              const float4 yb = *(const float4*)(br + gx);
              v = make_float4(yb.x - xa.x, yb.y - xa.y, yb.z - xa.z, yb.w - xa.w);
            } else {
              v = *(const float4*)(ar + gx);
            }
          } else {
            float tv[4] = {0.f, 0.f, 0.f, 0.f};
#pragma unroll
            for (int e = 0; e < 4; ++e) {
              const int gxe = gx + e;
              if (gxe >= 0 && gxe < WW)
                tv[e] = (MODE == 0) ? (br[gxe] - ar[gxe]) : ar[gxe];
            }
            v = make_float4(tv[0], tv[1], tv[2], tv[3]);
          }
        }
        *(float4*)(&lds[r * LSTR + c4 * 4]) = v;
      }
    }
  }
  __syncthreads();

  // ---- convolution from LDS: thread = 4 cols x 4 rows, diagonal reuse ----
  const int tc = tid & 31;                       // col-group 0..31
  const int tg = tid >> 5;                       // row-group 0..7 (4 rows each)
  const int lc = tc * 4;

  float acc[4][4];
#pragma unroll
  for (int t = 0; t < 4; ++t)
#pragma unroll
    for (int c = 0; c < 4; ++c) acc[t][c] = 0.0f;

#pragma unroll
  for (int rr = 0; rr < 20; ++rr) {
    const int lrow = tg * 4 + rr;
    const float* lp = &lds[lrow * LSTR];
    float win[WIN8 ? 8 : 4];
    if (WIN8) {
      // three aligned b128 reads at 16B lane stride: bank-conflict-free
      const float4 w0 = *(const float4*)(lp + 4 + lc);   // use .z .w
      const float4 w1 = *(const float4*)(lp + 8 + lc);
      const float4 w2 = *(const float4*)(lp + 12 + lc);  // use .x .y
      win[0] = w0.z;  win[1] = w0.w;
      win[2] = w1.x;  win[3] = w1.y;  win[4] = w1.z;  win[5] = w1.w;
      win[6] = w2.x;  win[7] = w2.y;
    } else {
      const float4 w1 = *(const float4*)(lp + lc);
      win[0] = w1.x;  win[1] = w1.y;  win[2] = w1.z;  win[3] = w1.w;
    }
#pragma unroll
    for (int t = 0; t < 4; ++t) {
      const int i = rr - t;                      // compile-time after unroll
      if (i >= 0 && i <= 16) {
        const int js = DENSE ? 0 : js_fn(ANGLE, i);
        const int nt = DENSE ? 5 : nt_fn(ANGLE, i);
#pragma unroll
        for (int jj = 0; jj < nt; ++jj) {
          const float wv = wts.w[i][js + jj];    // kernarg -> SGPR
#pragma unroll
          for (int c = 0; c < 4; ++c)
            acc[t][c] = fmaf(wv, win[(WIN8 ? 0 : -2) + c + js + jj], acc[t][c]);
        }
      }
    }
  }

  // ---- epilogue: cen from LDS; boundary renormalizes by knorm/N ----
  float* Ob = Out + img;
  const int gx = x0 + lc;
  const float kn = wts.knorm;
#pragma unroll
  for (int t = 0; t < 4; ++t) {
    const int yo = y0 + tg * 4 + t;
    const float4 cv = *(const float4*)(&lds[(tg * 4 + t + 8) * LSTR + XOFF + lc]);
    float a0 = acc[t][0], a1 = acc[t][1], a2 = acc[t][2], a3 = acc[t][3];
    if (!interior) {
      const float4 nv = *(const float4*)(Nrm + (size_t)yo * WW + gx);
      a0 = a0 * kn * fastrcp(nv.x);
      a1 = a1 * kn * fastrcp(nv.y);
      a2 = a2 * kn * fastrcp(nv.z);
      a3 = a3 * kn * fastrcp(nv.w);
    }
    float4 o;
    if (MODE == 2) {
      const float4 yv = *(const float4*)(Bp + (size_t)yo * WW + gx);
      o.x = yv.x - cv.x + a0;
      o.y = yv.y - cv.y + a1;
      o.z = yv.z - cv.z + a2;
      o.w = yv.w - cv.w + a3;
    } else {
      o.x = cv.x - a0;
      o.y = cv.y - a1;
      o.z = cv.z - a2;
      o.w = cv.w - a3;
    }
    *(float4*)(Ob + (size_t)yo * WW + gx) = o;
  }
}

// ---------------- host-side replication of _build_kernels ----------------

static void rotate33(const double* src, double* dst, double ang_deg) {
  const int n = 33;
  const double t = ang_deg * 3.14159265358979323846 / 180.0;
  const double cs = cos(t), sn = sin(t);
  for (int y = 0; y < n; ++y) {
    for (int x = 0; x < n; ++x) {
      const double y0 = y - 16.0, x0 = x - 16.0;
      const double sy = cs * y0 + sn * x0 + 16.0;
      const double sx = -sn * y0 + cs * x0 + 16.0;
      const double fy = floor(sy), fx = floor(sx);
      const int y0i = (int)fy, x0i = (int)fx;
      const double wy = sy - fy, wx = sx - fx;
      double o = 0.0;
      for (int dy = 0; dy < 2; ++dy)
        for (int dx = 0; dx < 2; ++dx) {
          const int yy = y0i + dy, xx = x0i + dx;
          if (yy < 0 || yy >= n || xx < 0 || xx >= n) continue;
          const double wgt = (dy ? wy : 1.0 - wy) * (dx ? wx : 1.0 - wx);
          o += wgt * src[yy * n + xx];
        }
      dst[y * n + x] = o;
    }
  }
}

static void build_K(float K[3][17][5]) {
  const double angs[3] = {-10.0, 0.0, 10.0};
  double base[33 * 33], rot[33 * 33];
  for (int i = 0; i < 33 * 33; ++i) base[i] = 0.0;
  for (int y = 0; y < 33; ++y) base[y * 33 + 16] = 1.0;  // ry==0 path
  for (int a = 0; a < 3; ++a) {
    if (a == 1) memcpy(rot, base, sizeof(rot));          // angle % 360 == 0
    else        rotate33(base, rot, angs[a]);
    double k17[17][17];
    for (int y = 0; y < 17; ++y)
      for (int x = 0; x < 17; ++x) k17[y][x] = rot[(y + 8) * 33 + (x + 8)];
    int r = 0, c = 0;
    for (int y = 0; y < 17; ++y) { bool nz = false; for (int x = 0; x < 17; ++x) if (k17[y][x] != 0.0) nz = true; r += nz; }
    for (int x = 0; x < 17; ++x) { bool nz = false; for (int y = 0; y < 17; ++y) if (k17[y][x] != 0.0) nz = true; c += nz; }
    r = r / 2 * 2; c = c / 2 * 2;
    const int kh = r + 1, kw = c + 1;
    for (int y = 0; y < 17; ++y)
      for (int x = 0; x < 5; ++x) K[a][y][x] = 0.0f;
    if (kh <= 17 && kw <= 5) {
      const int oh = (17 - kh) / 2, ow = (5 - kw) / 2;
      for (int y = 0; y < kh; ++y)
        for (int x = 0; x < kw; ++x)
          K[a][oh + y][ow + x] = (float)k17[8 - r / 2 + y][8 - c / 2 + x];
    }
  }
}

// 0 = structured (constexpr jstart/ntaps hold), 1 = dense 5-tap fallback
static int pick_mode(int a, const float K[17][5]) {
  for (int i = 0; i < 17; ++i) {
    const int js = js_fn(a, i), nt = nt_fn(a, i);
    for (int j = 0; j < 5; ++j)
      if ((j < js || j >= js + nt) && K[i][j] != 0.0f) return 1;
  }
  return 0;
}

template <int A, int MODE>
static void launch_iter(int dense, const float* P0, const float* P1, const float* Nrm,
                        float* Out, const Wts& w, int B, hipStream_t s) {
  dim3 grid(NTILES * B), blk(256);
  if (dense == 0) conv_iter<A, 0, MODE><<<grid, blk, 0, s>>>(P0, P1, Nrm, Out, w);
  else            conv_iter<A, 1, MODE><<<grid, blk, 0, s>>>(P0, P1, Nrm, Out, w);
}

extern "C" void kernel_launch(void* const* d_in, const int* in_sizes, int n_in,
                              void* d_out, int out_size, void* d_ws, size_t ws_size,
                              hipStream_t stream) {
  const float* X  = (const float*)d_in[0];
  const float* Y  = (const float*)d_in[1];
  const float* Nn = (const float*)d_in[3];
  float* out = (float*)d_out;
  float* tmp = (float*)d_ws;   // needs B*H*W*4 = 33.6 MB of scratch
  const size_t HW = (size_t)HH * WW;
  const int B = in_sizes[0] / (int)HW;   // 2

  float K[3][17][5];
  build_K(K);
  Wts w[3];
  for (int a = 0; a < 3; ++a) {
    double ks = 0.0;
    for (int i = 0; i < 17; ++i)
      for (int j = 0; j < 5; ++j) ks += K[a][i][j];
    const float kn = (float)ks;
    for (int i = 0; i < 17; ++i)
      for (int j = 0; j < 5; ++j) w[a].w[i][j] = K[a][i][j] / kn;
    w[a].knorm = kn;
  }
  const int m0 = pick_mode(0, K[0]);
  const int m1 = pick_mode(1, K[1]);
  const int m2 = pick_mode(2, K[2]);

  // D1 -> d_out, D2 -> d_ws, X3 -> d_out (never read+write same buffer in a pass)
  launch_iter<0, 0>(m0, X,   Y,       Nn,          out, w[0], B, stream);  // D1
  launch_iter<1, 1>(m1, out, nullptr, Nn + HW,     tmp, w[1], B, stream);  // D2
  launch_iter<2, 2>(m2, tmp, Y,       Nn + 2 * HW, out, w[2], B, stream);  // X3
}